// Round 8
// baseline (244.168 us; speedup 1.0000x reference)
//
#include <hip/hip_runtime.h>
#include <hip/hip_bf16.h>

#define LEAK 0.2f

typedef __attribute__((ext_vector_type(8))) short short8;
typedef __attribute__((ext_vector_type(4))) float f32x4;

union bfpack { int4 i; __hip_bfloat16 h[8]; };

// ---------- prep: W1,W2,T transpose+convert (1696 blocks) ----------
__global__ __launch_bounds__(256) void k_prep(const float* __restrict__ W1,
                                              __hip_bfloat16* __restrict__ W1t,
                                              const float* __restrict__ W2,
                                              __hip_bfloat16* __restrict__ W2t,
                                              const float* __restrict__ T,
                                              __hip_bfloat16* __restrict__ Tt) {
  __shared__ float tile[32][33];
  int b = blockIdx.x, t = threadIdx.x;
  const float* W;
  __hip_bfloat16* Wt;
  int K, N, kblk, nblk;
  if (b < 1536) {            // W1: 3072x512 -> 512x3072
    W = W1; Wt = W1t; K = 3072; N = 512;
    kblk = b % 96; nblk = b / 96;
  } else if (b < 1664) {     // W2: 512x256 -> 256x512
    int b3 = b - 1536;
    W = W2; Wt = W2t; K = 512; N = 256;
    kblk = b3 % 16; nblk = b3 / 16;
  } else {                   // T: 256x100 -> 128x256 (zero-pad)
    int b4 = b - 1664;
    W = T; Wt = Tt; K = 256; N = 100;
    kblk = b4 % 8; nblk = b4 / 8;
  }
  int k0 = kblk * 32, n0 = nblk * 32;
  int tx = t & 31, ty = t >> 5;
#pragma unroll
  for (int r = 0; r < 4; ++r) {
    int n = n0 + tx;
    tile[ty + r * 8][tx] = (n < N) ? W[(long)(k0 + ty + r * 8) * N + n] : 0.f;
  }
  __syncthreads();
#pragma unroll
  for (int r = 0; r < 4; ++r)
    Wt[(long)(n0 + ty + r * 8) * K + k0 + tx] = __float2bfloat16(tile[tx][ty + r * 8]);
}

// ---------- G1: P1[z] = x(fp32, convert-on-stage) @ W1t^T, split-K=3, BK=64 ----------
__global__ __launch_bounds__(256) void k_gemm1(const float* __restrict__ A,
                                               const __hip_bfloat16* __restrict__ Bt,
                                               float* __restrict__ Cp) {
  const int K = 3072, N = 512, KSPL = 1024;
  __shared__ __align__(16) __hip_bfloat16 As[64][72];
  __shared__ __align__(16) __hip_bfloat16 Bs[64][72];
  int tid = threadIdx.x, lane = tid & 63, wv = tid >> 6;
  int wm = wv & 1, wn = wv >> 1, quad = lane >> 4, l16 = lane & 15;
  long m0 = (long)blockIdx.x * 64, n0 = (long)blockIdx.y * 64;
  int kStart = blockIdx.z * KSPL;
  int srow = tid >> 2, scol = (tid & 3) * 16;
  const float* Ag = A + (m0 + srow) * K + kStart + scol;
  const __hip_bfloat16* Bg = Bt + (n0 + srow) * K + kStart + scol;

  auto loadA = [&](int kb, int4& o0, int4& o1) {
    float4 f0 = *reinterpret_cast<const float4*>(Ag + kb);
    float4 f1 = *reinterpret_cast<const float4*>(Ag + kb + 4);
    float4 f2 = *reinterpret_cast<const float4*>(Ag + kb + 8);
    float4 f3 = *reinterpret_cast<const float4*>(Ag + kb + 12);
    bfpack u0, u1;
    u0.h[0] = __float2bfloat16(f0.x); u0.h[1] = __float2bfloat16(f0.y);
    u0.h[2] = __float2bfloat16(f0.z); u0.h[3] = __float2bfloat16(f0.w);
    u0.h[4] = __float2bfloat16(f1.x); u0.h[5] = __float2bfloat16(f1.y);
    u0.h[6] = __float2bfloat16(f1.z); u0.h[7] = __float2bfloat16(f1.w);
    u1.h[0] = __float2bfloat16(f2.x); u1.h[1] = __float2bfloat16(f2.y);
    u1.h[2] = __float2bfloat16(f2.z); u1.h[3] = __float2bfloat16(f2.w);
    u1.h[4] = __float2bfloat16(f3.x); u1.h[5] = __float2bfloat16(f3.y);
    u1.h[6] = __float2bfloat16(f3.z); u1.h[7] = __float2bfloat16(f3.w);
    o0 = u0.i; o1 = u1.i;
  };

  int4 ra0, ra1, rb0, rb1;
  loadA(0, ra0, ra1);
  rb0 = *reinterpret_cast<const int4*>(Bg);
  rb1 = *reinterpret_cast<const int4*>(Bg + 8);

  f32x4 acc[2][2] = {};
  for (int kb = 0; kb < KSPL; kb += 64) {
    *reinterpret_cast<int4*>(&As[srow][scol]) = ra0;
    *reinterpret_cast<int4*>(&As[srow][scol + 8]) = ra1;
    *reinterpret_cast<int4*>(&Bs[srow][scol]) = rb0;
    *reinterpret_cast<int4*>(&Bs[srow][scol + 8]) = rb1;
    __syncthreads();
    if (kb + 64 < KSPL) {
      loadA(kb + 64, ra0, ra1);
      rb0 = *reinterpret_cast<const int4*>(Bg + kb + 64);
      rb1 = *reinterpret_cast<const int4*>(Bg + kb + 72);
    }
#pragma unroll
    for (int half = 0; half < 2; ++half) {
      short8 af[2], bfr[2];
#pragma unroll
      for (int u = 0; u < 2; ++u) {
        af[u]  = *reinterpret_cast<const short8*>(&As[wm * 32 + u * 16 + l16][half * 32 + quad * 8]);
        bfr[u] = *reinterpret_cast<const short8*>(&Bs[wn * 32 + u * 16 + l16][half * 32 + quad * 8]);
      }
#pragma unroll
      for (int tm = 0; tm < 2; ++tm)
#pragma unroll
        for (int tn = 0; tn < 2; ++tn)
          acc[tm][tn] =
              __builtin_amdgcn_mfma_f32_16x16x32_bf16(af[tm], bfr[tn], acc[tm][tn], 0, 0, 0);
    }
    __syncthreads();
  }

  float* Cz = Cp + (long)blockIdx.z * 2048 * 512;
#pragma unroll
  for (int tm = 0; tm < 2; ++tm)
#pragma unroll
    for (int tn = 0; tn < 2; ++tn)
#pragma unroll
      for (int r = 0; r < 4; ++r) {
        long gm = m0 + wm * 32 + tm * 16 + quad * 4 + r;
        long gn = n0 + wn * 32 + tn * 16 + l16;
        Cz[gm * N + gn] = acc[tm][tn][r];
      }
}

// ---------- G2: h2 = leaky(h1 @ W2t^T + b2); h1 built on-stage from 3 P1 partials ----------
__global__ __launch_bounds__(256) void k_gemm2(const float* __restrict__ P1,
                                               const float* __restrict__ b1,
                                               const __hip_bfloat16* __restrict__ Bt,
                                               const float* __restrict__ b2,
                                               __hip_bfloat16* __restrict__ h2b,
                                               float* __restrict__ h2f) {
  const int K = 512, N = 256;
  const long FS = 2048L * 512;
  __shared__ __align__(16) __hip_bfloat16 As[64][72];
  __shared__ __align__(16) __hip_bfloat16 Bs[64][72];
  int tid = threadIdx.x, lane = tid & 63, wv = tid >> 6;
  int wm = wv & 1, wn = wv >> 1, quad = lane >> 4, l16 = lane & 15;
  long m0 = (long)blockIdx.x * 64, n0 = (long)blockIdx.y * 64;
  int srow = tid >> 2, scol = (tid & 3) * 16;
  const float* Ag = P1 + (m0 + srow) * K + scol;
  const __hip_bfloat16* Bg = Bt + (n0 + srow) * K + scol;

  auto loadA = [&](int kb, int4& o0, int4& o1) {
    float4 v[4];
#pragma unroll
    for (int j = 0; j < 4; ++j) v[j] = *reinterpret_cast<const float4*>(Ag + kb + j * 4);
#pragma unroll
    for (int z = 1; z < 3; ++z)
#pragma unroll
      for (int j = 0; j < 4; ++j) {
        float4 a = *reinterpret_cast<const float4*>(Ag + z * FS + kb + j * 4);
        v[j].x += a.x; v[j].y += a.y; v[j].z += a.z; v[j].w += a.w;
      }
#pragma unroll
    for (int j = 0; j < 4; ++j) {
      float4 bs = *reinterpret_cast<const float4*>(b1 + kb + scol + j * 4);
      v[j].x += bs.x; v[j].y += bs.y; v[j].z += bs.z; v[j].w += bs.w;
      v[j].x = v[j].x > 0.f ? v[j].x : LEAK * v[j].x;
      v[j].y = v[j].y > 0.f ? v[j].y : LEAK * v[j].y;
      v[j].z = v[j].z > 0.f ? v[j].z : LEAK * v[j].z;
      v[j].w = v[j].w > 0.f ? v[j].w : LEAK * v[j].w;
    }
    bfpack u0, u1;
    u0.h[0] = __float2bfloat16(v[0].x); u0.h[1] = __float2bfloat16(v[0].y);
    u0.h[2] = __float2bfloat16(v[0].z); u0.h[3] = __float2bfloat16(v[0].w);
    u0.h[4] = __float2bfloat16(v[1].x); u0.h[5] = __float2bfloat16(v[1].y);
    u0.h[6] = __float2bfloat16(v[1].z); u0.h[7] = __float2bfloat16(v[1].w);
    u1.h[0] = __float2bfloat16(v[2].x); u1.h[1] = __float2bfloat16(v[2].y);
    u1.h[2] = __float2bfloat16(v[2].z); u1.h[3] = __float2bfloat16(v[2].w);
    u1.h[4] = __float2bfloat16(v[3].x); u1.h[5] = __float2bfloat16(v[3].y);
    u1.h[6] = __float2bfloat16(v[3].z); u1.h[7] = __float2bfloat16(v[3].w);
    o0 = u0.i; o1 = u1.i;
  };

  int4 ra0, ra1, rb0, rb1;
  loadA(0, ra0, ra1);
  rb0 = *reinterpret_cast<const int4*>(Bg);
  rb1 = *reinterpret_cast<const int4*>(Bg + 8);

  f32x4 acc[2][2] = {};
  for (int kb = 0; kb < K; kb += 64) {
    *reinterpret_cast<int4*>(&As[srow][scol]) = ra0;
    *reinterpret_cast<int4*>(&As[srow][scol + 8]) = ra1;
    *reinterpret_cast<int4*>(&Bs[srow][scol]) = rb0;
    *reinterpret_cast<int4*>(&Bs[srow][scol + 8]) = rb1;
    __syncthreads();
    if (kb + 64 < K) {
      loadA(kb + 64, ra0, ra1);
      rb0 = *reinterpret_cast<const int4*>(Bg + kb + 64);
      rb1 = *reinterpret_cast<const int4*>(Bg + kb + 72);
    }
#pragma unroll
    for (int half = 0; half < 2; ++half) {
      short8 af[2], bfr[2];
#pragma unroll
      for (int u = 0; u < 2; ++u) {
        af[u]  = *reinterpret_cast<const short8*>(&As[wm * 32 + u * 16 + l16][half * 32 + quad * 8]);
        bfr[u] = *reinterpret_cast<const short8*>(&Bs[wn * 32 + u * 16 + l16][half * 32 + quad * 8]);
      }
#pragma unroll
      for (int tm = 0; tm < 2; ++tm)
#pragma unroll
        for (int tn = 0; tn < 2; ++tn)
          acc[tm][tn] =
              __builtin_amdgcn_mfma_f32_16x16x32_bf16(af[tm], bfr[tn], acc[tm][tn], 0, 0, 0);
    }
    __syncthreads();
  }

#pragma unroll
  for (int tm = 0; tm < 2; ++tm)
#pragma unroll
    for (int tn = 0; tn < 2; ++tn)
#pragma unroll
      for (int r = 0; r < 4; ++r) {
        long gm = m0 + wm * 32 + tm * 16 + quad * 4 + r;
        long gn = n0 + wn * 32 + tn * 16 + l16;
        float v = acc[tm][tn][r] + b2[gn];
        v = v > 0.f ? v : LEAK * v;
        h2b[gm * N + gn] = __float2bfloat16(v);
        h2f[gm * N + gn] = v;
      }
}

// ---------- G3: P3[z] = (h2b @ Tt^T)^T, split-K=4; block(0,0,0) zeroes done-counter ----------
__global__ __launch_bounds__(256) void k_gemm3(const __hip_bfloat16* __restrict__ A,
                                               const __hip_bfloat16* __restrict__ Bt,
                                               float* __restrict__ Cp,
                                               unsigned* __restrict__ ctr) {
  const int K = 256;
  __shared__ __align__(16) __hip_bfloat16 As[64][72];
  __shared__ __align__(16) __hip_bfloat16 Bs[64][72];
  int tid = threadIdx.x;
  if (blockIdx.x == 0 && blockIdx.y == 0 && blockIdx.z == 0 && tid == 0)
    *ctr = 0;  // visible to k_bucketfinal via kernel-boundary ordering
  int lane = tid & 63, wv = tid >> 6;
  int wm = wv & 1, wn = wv >> 1, quad = lane >> 4, l16 = lane & 15;
  long m0 = (long)blockIdx.x * 64, n0 = (long)blockIdx.y * 64;
  int kStart = blockIdx.z * 64;
  int srow = tid >> 2, scol = (tid & 3) * 16;
  const __hip_bfloat16* Ag = A + (m0 + srow) * K + kStart + scol;
  const __hip_bfloat16* Bg = Bt + (n0 + srow) * K + kStart + scol;

  *reinterpret_cast<int4*>(&As[srow][scol]) = *reinterpret_cast<const int4*>(Ag);
  *reinterpret_cast<int4*>(&As[srow][scol + 8]) = *reinterpret_cast<const int4*>(Ag + 8);
  *reinterpret_cast<int4*>(&Bs[srow][scol]) = *reinterpret_cast<const int4*>(Bg);
  *reinterpret_cast<int4*>(&Bs[srow][scol + 8]) = *reinterpret_cast<const int4*>(Bg + 8);
  __syncthreads();
  f32x4 acc[2][2] = {};
#pragma unroll
  for (int half = 0; half < 2; ++half) {
    short8 af[2], bfr[2];
#pragma unroll
    for (int u = 0; u < 2; ++u) {
      af[u]  = *reinterpret_cast<const short8*>(&As[wm * 32 + u * 16 + l16][half * 32 + quad * 8]);
      bfr[u] = *reinterpret_cast<const short8*>(&Bs[wn * 32 + u * 16 + l16][half * 32 + quad * 8]);
    }
#pragma unroll
    for (int tm = 0; tm < 2; ++tm)
#pragma unroll
      for (int tn = 0; tn < 2; ++tn)
        acc[tm][tn] =
            __builtin_amdgcn_mfma_f32_16x16x32_bf16(af[tm], bfr[tn], acc[tm][tn], 0, 0, 0);
  }
  float* Cz = Cp + (long)blockIdx.z * 2048 * 128;
#pragma unroll
  for (int tm = 0; tm < 2; ++tm)
#pragma unroll
    for (int tn = 0; tn < 2; ++tn)
#pragma unroll
      for (int r = 0; r < 4; ++r) {
        long gm = m0 + wm * 32 + tm * 16 + quad * 4 + r;
        long gn = n0 + wn * 32 + tn * 16 + l16;
        Cz[gn * 2048 + gm] = acc[tm][tn][r];  // transposed partial: mTz[n][m]
      }
}

// ---------- bucketed features (blocks 0..99, plain stores) + counter-gated final ----------
// Producers write feT then release-increment ctr (100 atomics total).
// Finisher blocks 100..227 (128) spin (thread 0 only) until ctr==100, then
// compute out[i] = h2f[i,:].Wf + feT[:,i].Wf' + bf, one row per wave.
// Co-residency: 228 blocks x 16 waves, 52KB LDS -> 2 blocks/CU -> capacity 512.
__global__ __launch_bounds__(1024) void k_bucketfinal(const float* __restrict__ mTz,
                                                      const float* __restrict__ h2f,
                                                      const float* __restrict__ Wf,
                                                      const float* __restrict__ bfp,
                                                      float* __restrict__ feT,
                                                      unsigned* __restrict__ ctr,
                                                      float* __restrict__ out) {
  __shared__ float sP[2048], sN[2048];
  __shared__ float Sp[2048], Sn[2048];
  __shared__ int Smeta[2048];
  __shared__ short sB[2048];
  __shared__ int cnt[256], bstart[256], bcur[256];
  __shared__ float bsP[256], bsN[256], Pbel[256], Nab[256];
  __shared__ float wred[32];
  __shared__ float sMin, sMax;
  int blk = blockIdx.x;
  int t = threadIdx.x;
  int lane = t & 63, wv = t >> 6;

  if (blk >= 100) {  // finisher: wait for all 100 producers, then final dot
    if (t == 0) {
      while (__hip_atomic_load(ctr, __ATOMIC_ACQUIRE, __HIP_MEMORY_SCOPE_AGENT) != 100u)
        __builtin_amdgcn_s_sleep(8);
    }
    __syncthreads();
    __threadfence();
    long i = (long)(blk - 100) * 16 + wv;  // one row per wave, 128*16 = 2048 rows
    const float* hrow = h2f + i * 256;
    float s = 0.f;
#pragma unroll
    for (int c = lane; c < 256; c += 64) s += hrow[c] * Wf[c];
    for (int f2 = lane; f2 < 100; f2 += 64) s += feT[(long)f2 * 2048 + i] * Wf[256 + f2];
#pragma unroll
    for (int off = 32; off; off >>= 1) s += __shfl_down(s, off);
    if (lane == 0) out[i] = s + bfp[0];
    return;
  }

  int f = blk;
  const long FS = 2048L * 128;
  const float* row = mTz + (long)f * 2048;

  float m[2];
  float lmin = 3.4e38f, lmax = -3.4e38f;
#pragma unroll
  for (int r = 0; r < 2; ++r) {
    int e = t + r * 1024;
    float v = row[e] + row[FS + e] + row[2 * FS + e] + row[3 * FS + e];
    m[r] = v;
    lmin = fminf(lmin, v);
    lmax = fmaxf(lmax, v);
  }
#pragma unroll
  for (int d = 32; d; d >>= 1) {
    lmin = fminf(lmin, __shfl_down(lmin, d));
    lmax = fmaxf(lmax, __shfl_down(lmax, d));
  }
  if (lane == 0) { wred[wv] = lmin; wred[16 + wv] = lmax; }
  if (t < 256) cnt[t] = 0;
  __syncthreads();
  if (t == 0) {
    float a = wred[0], b = wred[16];
    for (int i = 1; i < 16; ++i) { a = fminf(a, wred[i]); b = fmaxf(b, wred[16 + i]); }
    sMin = a; sMax = b;
  }
  __syncthreads();
  float mn = sMin, mx = sMax;
  float rge = mx - mn;
  float scale = (rge > 1e-20f) ? 255.0f / rge : 0.f;
  float mid = 0.5f * (mn + mx);
#pragma unroll
  for (int r = 0; r < 2; ++r) {
    int e = t + r * 1024;
    float v = m[r];
    int b = (int)((v - mn) * scale);
    b = b < 255 ? b : 255;
    float arg = fminf(fmaxf(v - mid, -60.f), 60.f);
    sP[e] = __expf(arg);
    sN[e] = __expf(-arg);
    sB[e] = (short)b;
    atomicAdd(&cnt[b], 1);
  }
  __syncthreads();
  if (wv == 0) {  // exclusive prefix of cnt
    int b4 = lane * 4;
    int c0 = cnt[b4], c1 = cnt[b4 + 1], c2 = cnt[b4 + 2], c3 = cnt[b4 + 3];
    int tot = c0 + c1 + c2 + c3;
    int inc = tot;
#pragma unroll
    for (int d = 1; d < 64; d <<= 1) {
      int y = __shfl_up(inc, d);
      if (lane >= d) inc += y;
    }
    int run = inc - tot;
    bstart[b4] = run; bcur[b4] = run; run += c0;
    bstart[b4 + 1] = run; bcur[b4 + 1] = run; run += c1;
    bstart[b4 + 2] = run; bcur[b4 + 2] = run; run += c2;
    bstart[b4 + 3] = run; bcur[b4 + 3] = run;
  }
  __syncthreads();
#pragma unroll
  for (int r = 0; r < 2; ++r) {  // scatter into bucket order
    int e = t + r * 1024;
    int b = sB[e];
    int slot = atomicAdd(&bcur[b], 1);
    Sp[slot] = sP[e];
    Sn[slot] = sN[e];
    Smeta[slot] = (b << 16) | e;
  }
  __syncthreads();
  if (t < 256) {  // per-bucket sums
    int s0 = bstart[t], s1 = s0 + cnt[t];
    float ap = 0.f, an = 0.f;
    for (int q = s0; q < s1; ++q) { ap += Sp[q]; an += Sn[q]; }
    bsP[t] = ap; bsN[t] = an;
  }
  __syncthreads();
  if (wv == 0) {  // bucket-level exclusive prefix(P) / suffix(N)
    int b4 = lane * 4;
    float p0 = bsP[b4], p1 = bsP[b4 + 1], p2 = bsP[b4 + 2], p3 = bsP[b4 + 3];
    float n0 = bsN[b4], n1 = bsN[b4 + 1], n2 = bsN[b4 + 2], n3 = bsN[b4 + 3];
    float tp = p0 + p1 + p2 + p3, tn = n0 + n1 + n2 + n3;
    float ip = tp, in_ = tn;
#pragma unroll
    for (int d = 1; d < 64; d <<= 1) {
      float yp = __shfl_up(ip, d);
      float yn = __shfl_up(in_, d);
      if (lane >= d) { ip += yp; in_ += yn; }
    }
    float totn = __shfl(in_, 63);
    float runp = ip - tp;
    float runn = in_ - tn;
    Pbel[b4] = runp; Nab[b4] = totn - runn - n0; runp += p0; runn += n0;
    Pbel[b4 + 1] = runp; Nab[b4 + 1] = totn - runn - n1; runp += p1; runn += n1;
    Pbel[b4 + 2] = runp; Nab[b4 + 2] = totn - runn - n2; runp += p2; runn += n2;
    Pbel[b4 + 3] = runp; Nab[b4 + 3] = totn - runn - n3;
  }
  __syncthreads();
#pragma unroll
  for (int r = 0; r < 2; ++r) {
    int s = t + r * 1024;
    int meta = Smeta[s];
    int b = meta >> 16;
    int idx = meta & 0xFFFF;
    float p = Sp[s], n = Sn[s];
    float acc = n * Pbel[b] + p * Nab[b];
    int q0 = bstart[b], q1 = q0 + cnt[b];
    for (int q = q0; q < q1; ++q) acc += fminf(p * Sn[q], n * Sp[q]);
    feT[(long)f * 2048 + idx] = acc;  // plain coalesced-ish store, no atomics
  }
  // release: publish this feature's 2048 results
  __threadfence();
  __syncthreads();
  if (t == 0)
    __hip_atomic_fetch_add(ctr, 1u, __ATOMIC_RELEASE, __HIP_MEMORY_SCOPE_AGENT);
}

extern "C" void kernel_launch(void* const* d_in, const int* in_sizes, int n_in,
                              void* d_out, int out_size, void* d_ws, size_t ws_size,
                              hipStream_t stream) {
  const float* x  = (const float*)d_in[0];
  const float* W1 = (const float*)d_in[1];
  const float* b1 = (const float*)d_in[2];
  const float* W2 = (const float*)d_in[3];
  const float* b2 = (const float*)d_in[4];
  const float* T  = (const float*)d_in[5];
  const float* Wf = (const float*)d_in[6];
  const float* bf = (const float*)d_in[7];
  float* out = (float*)d_out;

  char* w = (char*)d_ws;
  auto alloc = [&](size_t b) { char* p = w; w += (b + 255) & ~(size_t)255; return p; };
  __hip_bfloat16* W1t = (__hip_bfloat16*)alloc(512L * 3072 * 2);   // 3 MB
  __hip_bfloat16* W2t = (__hip_bfloat16*)alloc(256L * 512 * 2);
  __hip_bfloat16* Tt  = (__hip_bfloat16*)alloc(128L * 256 * 2);
  float*          h2f = (float*)alloc(2048L * 256 * 4);            // 2 MB
  __hip_bfloat16* h2b = (__hip_bfloat16*)alloc(2048L * 256 * 2);   // 1 MB
  float*          feT = (float*)alloc(100L * 2048 * 4);            // 0.8 MB
  float*          P1  = (float*)alloc(3L * 2048 * 512 * 4);        // 12 MB
  float*          P3  = (float*)alloc(4L * 2048 * 128 * 4);        // 4 MB
  unsigned*       ctr = (unsigned*)alloc(256);

  // 1) weight transposes
  k_prep<<<1696, 256, 0, stream>>>(W1, W1t, W2, W2t, T, Tt);
  // 2) G1: x(fp32) @ W1t, convert-on-stage, split-K=3
  k_gemm1<<<dim3(32, 8, 3), 256, 0, stream>>>(x, W1t, P1);
  // 3) G2: (comb1 fused on stage) @ W2t, full-K, fused b2+leaky -> h2b+h2f
  k_gemm2<<<dim3(32, 4), 256, 0, stream>>>(P1, b1, W2t, b2, h2b, h2f);
  // 4) G3: h2b @ Tt, split-K=4, transposed partials; zeroes ctr
  k_gemm3<<<dim3(32, 2, 4), 256, 0, stream>>>(h2b, Tt, P3, ctr);
  // 5) bucketed features (100 producers) + counter-gated final dot (128 finishers)
  k_bucketfinal<<<228, 1024, 0, stream>>>(P3, h2f, Wf, bf, feT, ctr, out);
}

// Round 9
// 136.658 us; speedup vs baseline: 1.7867x; 1.7867x over previous
//
#include <hip/hip_runtime.h>
#include <hip/hip_bf16.h>

#define LEAK 0.2f

typedef __attribute__((ext_vector_type(8))) short short8;
typedef __attribute__((ext_vector_type(4))) float f32x4;

union bfpack { int4 i; __hip_bfloat16 h[8]; };

// ---------- transpose tile body: W[K][N] fp32 -> Wt[n0+32][k0+32] bf16 ----------
__device__ __forceinline__ void transpose_tile(float (*tile)[33], int t,
                                               const float* __restrict__ W,
                                               __hip_bfloat16* __restrict__ Wt,
                                               int K, int N, int kblk, int nblk) {
  int k0 = kblk * 32, n0 = nblk * 32;
  int tx = t & 31, ty = t >> 5;
#pragma unroll
  for (int r = 0; r < 4; ++r) {
    int n = n0 + tx;
    tile[ty + r * 8][tx] = (n < N) ? W[(long)(k0 + ty + r * 8) * N + n] : 0.f;
  }
  __syncthreads();
#pragma unroll
  for (int r = 0; r < 4; ++r)
    Wt[(long)(n0 + ty + r * 8) * K + k0 + tx] = __float2bfloat16(tile[tx][ty + r * 8]);
}

// ---------- prep: W1 transpose only (1536 blocks) ----------
__global__ __launch_bounds__(256) void k_prep(const float* __restrict__ W1,
                                              __hip_bfloat16* __restrict__ W1t) {
  __shared__ float tile[32][33];
  int b = blockIdx.x;
  transpose_tile(tile, threadIdx.x, W1, W1t, 3072, 512, b % 96, b / 96);
}

// ---------- G1: P1[z] = x(fp32, convert-on-stage) @ W1t^T, split-K=3, BK=64 ----------
// 1D grid: [0,768) GEMM tiles; [768,896) W2t transpose; [896,928) Tt transpose.
__global__ __launch_bounds__(256) void k_gemm1(const float* __restrict__ A,
                                               const __hip_bfloat16* __restrict__ Bt,
                                               float* __restrict__ Cp,
                                               const float* __restrict__ W2,
                                               __hip_bfloat16* __restrict__ W2t,
                                               const float* __restrict__ T,
                                               __hip_bfloat16* __restrict__ Tt) {
  const int K = 3072, N = 512, KSPL = 1024;
  __shared__ __align__(16) __hip_bfloat16 As[64][72];
  __shared__ __align__(16) __hip_bfloat16 Bs[64][72];
  int gid = blockIdx.x;
  int tid = threadIdx.x;
  if (gid >= 768) {  // side blocks: W2t / Tt transposes (outputs used by G2/G3 only)
    float (*tile)[33] = (float(*)[33])&As[0][0];
    int b = gid - 768;
    if (b < 128) transpose_tile(tile, tid, W2, W2t, 512, 256, b % 16, b / 16);
    else { b -= 128; transpose_tile(tile, tid, T, Tt, 256, 100, b % 8, b / 8); }
    return;
  }
  int mt = gid & 31, nt = (gid >> 5) & 7, z = gid >> 8;
  int lane = tid & 63, wv = tid >> 6;
  int wm = wv & 1, wn = wv >> 1, quad = lane >> 4, l16 = lane & 15;
  long m0 = (long)mt * 64, n0 = (long)nt * 64;
  int kStart = z * KSPL;
  int srow = tid >> 2, scol = (tid & 3) * 16;
  const float* Ag = A + (m0 + srow) * K + kStart + scol;
  const __hip_bfloat16* Bg = Bt + (n0 + srow) * K + kStart + scol;

  auto loadA = [&](int kb, int4& o0, int4& o1) {
    float4 f0 = *reinterpret_cast<const float4*>(Ag + kb);
    float4 f1 = *reinterpret_cast<const float4*>(Ag + kb + 4);
    float4 f2 = *reinterpret_cast<const float4*>(Ag + kb + 8);
    float4 f3 = *reinterpret_cast<const float4*>(Ag + kb + 12);
    bfpack u0, u1;
    u0.h[0] = __float2bfloat16(f0.x); u0.h[1] = __float2bfloat16(f0.y);
    u0.h[2] = __float2bfloat16(f0.z); u0.h[3] = __float2bfloat16(f0.w);
    u0.h[4] = __float2bfloat16(f1.x); u0.h[5] = __float2bfloat16(f1.y);
    u0.h[6] = __float2bfloat16(f1.z); u0.h[7] = __float2bfloat16(f1.w);
    u1.h[0] = __float2bfloat16(f2.x); u1.h[1] = __float2bfloat16(f2.y);
    u1.h[2] = __float2bfloat16(f2.z); u1.h[3] = __float2bfloat16(f2.w);
    u1.h[4] = __float2bfloat16(f3.x); u1.h[5] = __float2bfloat16(f3.y);
    u1.h[6] = __float2bfloat16(f3.z); u1.h[7] = __float2bfloat16(f3.w);
    o0 = u0.i; o1 = u1.i;
  };

  int4 ra0, ra1, rb0, rb1;
  loadA(0, ra0, ra1);
  rb0 = *reinterpret_cast<const int4*>(Bg);
  rb1 = *reinterpret_cast<const int4*>(Bg + 8);

  f32x4 acc[2][2] = {};
  for (int kb = 0; kb < KSPL; kb += 64) {
    *reinterpret_cast<int4*>(&As[srow][scol]) = ra0;
    *reinterpret_cast<int4*>(&As[srow][scol + 8]) = ra1;
    *reinterpret_cast<int4*>(&Bs[srow][scol]) = rb0;
    *reinterpret_cast<int4*>(&Bs[srow][scol + 8]) = rb1;
    __syncthreads();
    if (kb + 64 < KSPL) {
      loadA(kb + 64, ra0, ra1);
      rb0 = *reinterpret_cast<const int4*>(Bg + kb + 64);
      rb1 = *reinterpret_cast<const int4*>(Bg + kb + 72);
    }
#pragma unroll
    for (int half = 0; half < 2; ++half) {
      short8 af[2], bfr[2];
#pragma unroll
      for (int u = 0; u < 2; ++u) {
        af[u]  = *reinterpret_cast<const short8*>(&As[wm * 32 + u * 16 + l16][half * 32 + quad * 8]);
        bfr[u] = *reinterpret_cast<const short8*>(&Bs[wn * 32 + u * 16 + l16][half * 32 + quad * 8]);
      }
#pragma unroll
      for (int tm = 0; tm < 2; ++tm)
#pragma unroll
        for (int tn = 0; tn < 2; ++tn)
          acc[tm][tn] =
              __builtin_amdgcn_mfma_f32_16x16x32_bf16(af[tm], bfr[tn], acc[tm][tn], 0, 0, 0);
    }
    __syncthreads();
  }

  float* Cz = Cp + (long)z * 2048 * 512;
#pragma unroll
  for (int tm = 0; tm < 2; ++tm)
#pragma unroll
    for (int tn = 0; tn < 2; ++tn)
#pragma unroll
      for (int r = 0; r < 4; ++r) {
        long gm = m0 + wm * 32 + tm * 16 + quad * 4 + r;
        long gn = n0 + wn * 32 + tn * 16 + l16;
        Cz[gm * N + gn] = acc[tm][tn][r];
      }
}

// ---------- G2: h2 = leaky(h1 @ W2t^T + b2); h1 built on-stage from 3 P1 partials ----------
__global__ __launch_bounds__(256) void k_gemm2(const float* __restrict__ P1,
                                               const float* __restrict__ b1,
                                               const __hip_bfloat16* __restrict__ Bt,
                                               const float* __restrict__ b2,
                                               __hip_bfloat16* __restrict__ h2b,
                                               float* __restrict__ h2f) {
  const int K = 512, N = 256;
  const long FS = 2048L * 512;
  __shared__ __align__(16) __hip_bfloat16 As[64][72];
  __shared__ __align__(16) __hip_bfloat16 Bs[64][72];
  int tid = threadIdx.x, lane = tid & 63, wv = tid >> 6;
  int wm = wv & 1, wn = wv >> 1, quad = lane >> 4, l16 = lane & 15;
  long m0 = (long)blockIdx.x * 64, n0 = (long)blockIdx.y * 64;
  int srow = tid >> 2, scol = (tid & 3) * 16;
  const float* Ag = P1 + (m0 + srow) * K + scol;
  const __hip_bfloat16* Bg = Bt + (n0 + srow) * K + scol;

  auto loadA = [&](int kb, int4& o0, int4& o1) {
    float4 v[4];
#pragma unroll
    for (int j = 0; j < 4; ++j) v[j] = *reinterpret_cast<const float4*>(Ag + kb + j * 4);
#pragma unroll
    for (int z = 1; z < 3; ++z)
#pragma unroll
      for (int j = 0; j < 4; ++j) {
        float4 a = *reinterpret_cast<const float4*>(Ag + z * FS + kb + j * 4);
        v[j].x += a.x; v[j].y += a.y; v[j].z += a.z; v[j].w += a.w;
      }
#pragma unroll
    for (int j = 0; j < 4; ++j) {
      float4 bs = *reinterpret_cast<const float4*>(b1 + kb + scol + j * 4);
      v[j].x += bs.x; v[j].y += bs.y; v[j].z += bs.z; v[j].w += bs.w;
      v[j].x = v[j].x > 0.f ? v[j].x : LEAK * v[j].x;
      v[j].y = v[j].y > 0.f ? v[j].y : LEAK * v[j].y;
      v[j].z = v[j].z > 0.f ? v[j].z : LEAK * v[j].z;
      v[j].w = v[j].w > 0.f ? v[j].w : LEAK * v[j].w;
    }
    bfpack u0, u1;
    u0.h[0] = __float2bfloat16(v[0].x); u0.h[1] = __float2bfloat16(v[0].y);
    u0.h[2] = __float2bfloat16(v[0].z); u0.h[3] = __float2bfloat16(v[0].w);
    u0.h[4] = __float2bfloat16(v[1].x); u0.h[5] = __float2bfloat16(v[1].y);
    u0.h[6] = __float2bfloat16(v[1].z); u0.h[7] = __float2bfloat16(v[1].w);
    u1.h[0] = __float2bfloat16(v[2].x); u1.h[1] = __float2bfloat16(v[2].y);
    u1.h[2] = __float2bfloat16(v[2].z); u1.h[3] = __float2bfloat16(v[2].w);
    u1.h[4] = __float2bfloat16(v[3].x); u1.h[5] = __float2bfloat16(v[3].y);
    u1.h[6] = __float2bfloat16(v[3].z); u1.h[7] = __float2bfloat16(v[3].w);
    o0 = u0.i; o1 = u1.i;
  };

  int4 ra0, ra1, rb0, rb1;
  loadA(0, ra0, ra1);
  rb0 = *reinterpret_cast<const int4*>(Bg);
  rb1 = *reinterpret_cast<const int4*>(Bg + 8);

  f32x4 acc[2][2] = {};
  for (int kb = 0; kb < K; kb += 64) {
    *reinterpret_cast<int4*>(&As[srow][scol]) = ra0;
    *reinterpret_cast<int4*>(&As[srow][scol + 8]) = ra1;
    *reinterpret_cast<int4*>(&Bs[srow][scol]) = rb0;
    *reinterpret_cast<int4*>(&Bs[srow][scol + 8]) = rb1;
    __syncthreads();
    if (kb + 64 < K) {
      loadA(kb + 64, ra0, ra1);
      rb0 = *reinterpret_cast<const int4*>(Bg + kb + 64);
      rb1 = *reinterpret_cast<const int4*>(Bg + kb + 72);
    }
#pragma unroll
    for (int half = 0; half < 2; ++half) {
      short8 af[2], bfr[2];
#pragma unroll
      for (int u = 0; u < 2; ++u) {
        af[u]  = *reinterpret_cast<const short8*>(&As[wm * 32 + u * 16 + l16][half * 32 + quad * 8]);
        bfr[u] = *reinterpret_cast<const short8*>(&Bs[wn * 32 + u * 16 + l16][half * 32 + quad * 8]);
      }
#pragma unroll
      for (int tm = 0; tm < 2; ++tm)
#pragma unroll
        for (int tn = 0; tn < 2; ++tn)
          acc[tm][tn] =
              __builtin_amdgcn_mfma_f32_16x16x32_bf16(af[tm], bfr[tn], acc[tm][tn], 0, 0, 0);
    }
    __syncthreads();
  }

#pragma unroll
  for (int tm = 0; tm < 2; ++tm)
#pragma unroll
    for (int tn = 0; tn < 2; ++tn)
#pragma unroll
      for (int r = 0; r < 4; ++r) {
        long gm = m0 + wm * 32 + tm * 16 + quad * 4 + r;
        long gn = n0 + wn * 32 + tn * 16 + l16;
        float v = acc[tm][tn][r] + b2[gn];
        v = v > 0.f ? v : LEAK * v;
        h2b[gm * N + gn] = __float2bfloat16(v);
        h2f[gm * N + gn] = v;
      }
}

// ---------- G3: P3[z] = (h2b @ Tt^T)^T, split-K=4, transposed partials ----------
__global__ __launch_bounds__(256) void k_gemm3(const __hip_bfloat16* __restrict__ A,
                                               const __hip_bfloat16* __restrict__ Bt,
                                               float* __restrict__ Cp) {
  const int K = 256;
  __shared__ __align__(16) __hip_bfloat16 As[64][72];
  __shared__ __align__(16) __hip_bfloat16 Bs[64][72];
  int tid = threadIdx.x;
  int lane = tid & 63, wv = tid >> 6;
  int wm = wv & 1, wn = wv >> 1, quad = lane >> 4, l16 = lane & 15;
  long m0 = (long)blockIdx.x * 64, n0 = (long)blockIdx.y * 64;
  int kStart = blockIdx.z * 64;
  int srow = tid >> 2, scol = (tid & 3) * 16;
  const __hip_bfloat16* Ag = A + (m0 + srow) * K + kStart + scol;
  const __hip_bfloat16* Bg = Bt + (n0 + srow) * K + kStart + scol;

  *reinterpret_cast<int4*>(&As[srow][scol]) = *reinterpret_cast<const int4*>(Ag);
  *reinterpret_cast<int4*>(&As[srow][scol + 8]) = *reinterpret_cast<const int4*>(Ag + 8);
  *reinterpret_cast<int4*>(&Bs[srow][scol]) = *reinterpret_cast<const int4*>(Bg);
  *reinterpret_cast<int4*>(&Bs[srow][scol + 8]) = *reinterpret_cast<const int4*>(Bg + 8);
  __syncthreads();
  f32x4 acc[2][2] = {};
#pragma unroll
  for (int half = 0; half < 2; ++half) {
    short8 af[2], bfr[2];
#pragma unroll
    for (int u = 0; u < 2; ++u) {
      af[u]  = *reinterpret_cast<const short8*>(&As[wm * 32 + u * 16 + l16][half * 32 + quad * 8]);
      bfr[u] = *reinterpret_cast<const short8*>(&Bs[wn * 32 + u * 16 + l16][half * 32 + quad * 8]);
    }
#pragma unroll
    for (int tm = 0; tm < 2; ++tm)
#pragma unroll
      for (int tn = 0; tn < 2; ++tn)
        acc[tm][tn] =
            __builtin_amdgcn_mfma_f32_16x16x32_bf16(af[tm], bfr[tn], acc[tm][tn], 0, 0, 0);
  }
  float* Cz = Cp + (long)blockIdx.z * 2048 * 128;
#pragma unroll
  for (int tm = 0; tm < 2; ++tm)
#pragma unroll
    for (int tn = 0; tn < 2; ++tn)
#pragma unroll
      for (int r = 0; r < 4; ++r) {
        long gm = m0 + wm * 32 + tm * 16 + quad * 4 + r;
        long gn = n0 + wn * 32 + tn * 16 + l16;
        Cz[gn * 2048 + gm] = acc[tm][tn][r];  // transposed partial: mTz[n][m]
      }
}

// ---------- bucketed minibatch-discrimination features, O(B) ----------
__global__ __launch_bounds__(1024) void k_bucketfeats(const float* __restrict__ mTz,
                                                      float* __restrict__ featsT) {
  __shared__ float sP[2048], sN[2048];
  __shared__ float Sp[2048], Sn[2048];
  __shared__ int Smeta[2048];
  __shared__ short sB[2048];
  __shared__ int cnt[256], bstart[256], bcur[256];
  __shared__ float bsP[256], bsN[256], Pbel[256], Nab[256];
  __shared__ float wred[32];
  __shared__ float sMin, sMax;
  int f = blockIdx.x;
  int t = threadIdx.x;
  int lane = t & 63, wv = t >> 6;
  const long FS = 2048L * 128;
  const float* row = mTz + (long)f * 2048;

  float m[2];
  float lmin = 3.4e38f, lmax = -3.4e38f;
#pragma unroll
  for (int r = 0; r < 2; ++r) {
    int e = t + r * 1024;
    float v = row[e] + row[FS + e] + row[2 * FS + e] + row[3 * FS + e];
    m[r] = v;
    lmin = fminf(lmin, v);
    lmax = fmaxf(lmax, v);
  }
#pragma unroll
  for (int d = 32; d; d >>= 1) {
    lmin = fminf(lmin, __shfl_down(lmin, d));
    lmax = fmaxf(lmax, __shfl_down(lmax, d));
  }
  if (lane == 0) { wred[wv] = lmin; wred[16 + wv] = lmax; }
  if (t < 256) cnt[t] = 0;
  __syncthreads();
  if (t == 0) {
    float a = wred[0], b = wred[16];
    for (int i = 1; i < 16; ++i) { a = fminf(a, wred[i]); b = fmaxf(b, wred[16 + i]); }
    sMin = a; sMax = b;
  }
  __syncthreads();
  float mn = sMin, mx = sMax;
  float rge = mx - mn;
  float scale = (rge > 1e-20f) ? 255.0f / rge : 0.f;
  float mid = 0.5f * (mn + mx);
#pragma unroll
  for (int r = 0; r < 2; ++r) {
    int e = t + r * 1024;
    float v = m[r];
    int b = (int)((v - mn) * scale);
    b = b < 255 ? b : 255;
    float arg = fminf(fmaxf(v - mid, -60.f), 60.f);
    sP[e] = __expf(arg);
    sN[e] = __expf(-arg);
    sB[e] = (short)b;
    atomicAdd(&cnt[b], 1);
  }
  __syncthreads();
  if (wv == 0) {
    int b4 = lane * 4;
    int c0 = cnt[b4], c1 = cnt[b4 + 1], c2 = cnt[b4 + 2], c3 = cnt[b4 + 3];
    int tot = c0 + c1 + c2 + c3;
    int inc = tot;
#pragma unroll
    for (int d = 1; d < 64; d <<= 1) {
      int y = __shfl_up(inc, d);
      if (lane >= d) inc += y;
    }
    int run = inc - tot;
    bstart[b4] = run; bcur[b4] = run; run += c0;
    bstart[b4 + 1] = run; bcur[b4 + 1] = run; run += c1;
    bstart[b4 + 2] = run; bcur[b4 + 2] = run; run += c2;
    bstart[b4 + 3] = run; bcur[b4 + 3] = run;
  }
  __syncthreads();
#pragma unroll
  for (int r = 0; r < 2; ++r) {
    int e = t + r * 1024;
    int b = sB[e];
    int slot = atomicAdd(&bcur[b], 1);
    Sp[slot] = sP[e];
    Sn[slot] = sN[e];
    Smeta[slot] = (b << 16) | e;
  }
  __syncthreads();
  if (t < 256) {
    int s0 = bstart[t], s1 = s0 + cnt[t];
    float ap = 0.f, an = 0.f;
    for (int q = s0; q < s1; ++q) { ap += Sp[q]; an += Sn[q]; }
    bsP[t] = ap; bsN[t] = an;
  }
  __syncthreads();
  if (wv == 0) {
    int b4 = lane * 4;
    float p0 = bsP[b4], p1 = bsP[b4 + 1], p2 = bsP[b4 + 2], p3 = bsP[b4 + 3];
    float n0 = bsN[b4], n1 = bsN[b4 + 1], n2 = bsN[b4 + 2], n3 = bsN[b4 + 3];
    float tp = p0 + p1 + p2 + p3, tn = n0 + n1 + n2 + n3;
    float ip = tp, in_ = tn;
#pragma unroll
    for (int d = 1; d < 64; d <<= 1) {
      float yp = __shfl_up(ip, d);
      float yn = __shfl_up(in_, d);
      if (lane >= d) { ip += yp; in_ += yn; }
    }
    float totn = __shfl(in_, 63);
    float runp = ip - tp;
    float runn = in_ - tn;
    Pbel[b4] = runp; Nab[b4] = totn - runn - n0; runp += p0; runn += n0;
    Pbel[b4 + 1] = runp; Nab[b4 + 1] = totn - runn - n1; runp += p1; runn += n1;
    Pbel[b4 + 2] = runp; Nab[b4 + 2] = totn - runn - n2; runp += p2; runn += n2;
    Pbel[b4 + 3] = runp; Nab[b4 + 3] = totn - runn - n3;
  }
  __syncthreads();
#pragma unroll
  for (int r = 0; r < 2; ++r) {
    int s = t + r * 1024;
    int meta = Smeta[s];
    int b = meta >> 16;
    int idx = meta & 0xFFFF;
    float p = Sp[s], n = Sn[s];
    float acc = n * Pbel[b] + p * Nab[b];
    int q0 = bstart[b], q1 = q0 + cnt[b];
    for (int q = q0; q < q1; ++q) acc += fminf(p * Sn[q], n * Sp[q]);
    featsT[(long)f * 2048 + idx] = acc;
  }
}

// ---------- final: out[i] = h2f[i,:].Wf[0:256] + featsT[:,i].Wf[256:356] + bf ----------
__global__ __launch_bounds__(256) void k_final(const float* __restrict__ h2f,
                                               const float* __restrict__ featsT,
                                               const float* __restrict__ Wf,
                                               const float* __restrict__ bfp,
                                               float* __restrict__ out) {
  int wv = threadIdx.x >> 6, lane = threadIdx.x & 63;
  long i = (long)blockIdx.x * 4 + wv;
  const float* hrow = h2f + i * 256;
  float s = 0.f;
#pragma unroll
  for (int c = lane; c < 256; c += 64) s += hrow[c] * Wf[c];
  for (int f = lane; f < 100; f += 64) s += featsT[(long)f * 2048 + i] * Wf[256 + f];
#pragma unroll
  for (int off = 32; off; off >>= 1) s += __shfl_down(s, off);
  if (lane == 0) out[i] = s + bfp[0];
}

extern "C" void kernel_launch(void* const* d_in, const int* in_sizes, int n_in,
                              void* d_out, int out_size, void* d_ws, size_t ws_size,
                              hipStream_t stream) {
  const float* x  = (const float*)d_in[0];
  const float* W1 = (const float*)d_in[1];
  const float* b1 = (const float*)d_in[2];
  const float* W2 = (const float*)d_in[3];
  const float* b2 = (const float*)d_in[4];
  const float* T  = (const float*)d_in[5];
  const float* Wf = (const float*)d_in[6];
  const float* bf = (const float*)d_in[7];
  float* out = (float*)d_out;

  char* w = (char*)d_ws;
  auto alloc = [&](size_t b) { char* p = w; w += (b + 255) & ~(size_t)255; return p; };
  __hip_bfloat16* W1t = (__hip_bfloat16*)alloc(512L * 3072 * 2);   // 3 MB
  __hip_bfloat16* W2t = (__hip_bfloat16*)alloc(256L * 512 * 2);
  __hip_bfloat16* Tt  = (__hip_bfloat16*)alloc(128L * 256 * 2);
  float*          h2f = (float*)alloc(2048L * 256 * 4);            // 2 MB
  __hip_bfloat16* h2b = (__hip_bfloat16*)alloc(2048L * 256 * 2);   // 1 MB
  float*          feT = (float*)alloc(100L * 2048 * 4);            // 0.8 MB
  float*          P1  = (float*)alloc(3L * 2048 * 512 * 4);        // 12 MB
  float*          P3  = (float*)alloc(4L * 2048 * 128 * 4);        // 4 MB

  // 1) W1 transpose
  k_prep<<<1536, 256, 0, stream>>>(W1, W1t);
  // 2) G1: x(fp32) @ W1t, convert-on-stage, split-K=3; + W2t/Tt side-blocks
  k_gemm1<<<928, 256, 0, stream>>>(x, W1t, P1, W2, W2t, T, Tt);
  // 3) G2: (comb1 fused on stage) @ W2t, full-K, fused b2+leaky -> h2b+h2f
  k_gemm2<<<dim3(32, 4), 256, 0, stream>>>(P1, b1, W2t, b2, h2b, h2f);
  // 4) G3: h2b @ Tt, split-K=4, transposed partials
  k_gemm3<<<dim3(32, 2, 4), 256, 0, stream>>>(h2b, Tt, P3);
  // 5) bucketed features (plain stores)
  k_bucketfeats<<<100, 1024, 0, stream>>>(P3, feT);
  // 6) final dot
  k_final<<<512, 256, 0, stream>>>(h2f, feT, Wf, bf, out);
}

// Round 10
// 132.511 us; speedup vs baseline: 1.8426x; 1.0313x over previous
//
#include <hip/hip_runtime.h>
#include <hip/hip_bf16.h>

#define LEAK 0.2f

typedef __attribute__((ext_vector_type(8))) short short8;
typedef __attribute__((ext_vector_type(4))) float f32x4;

union bfpack { int4 i; __hip_bfloat16 h[8]; };

__device__ __forceinline__ float bf2f(unsigned short u) {
  union { unsigned v; float f; } c;
  c.v = ((unsigned)u) << 16;
  return c.f;
}

// ---------- fused prep: x->bf16 convert ++ W1,W2,T transpose+convert ----------
// grid: [0,6144) convert, [6144,7680) W1t, [7680,7808) W2t, [7808,7840) Tt
__global__ __launch_bounds__(256) void k_prep(const float* __restrict__ x,
                                              __hip_bfloat16* __restrict__ xb,
                                              const float* __restrict__ W1,
                                              __hip_bfloat16* __restrict__ W1t,
                                              const float* __restrict__ W2,
                                              __hip_bfloat16* __restrict__ W2t,
                                              const float* __restrict__ T,
                                              __hip_bfloat16* __restrict__ Tt) {
  int b = blockIdx.x;
  int t = threadIdx.x;
  if (b < 6144) {
    int idx = b * 256 + t;
    float4 v = reinterpret_cast<const float4*>(x)[idx];
    union { ushort4 u; __hip_bfloat16 h[4]; } c;
    c.h[0] = __float2bfloat16(v.x);
    c.h[1] = __float2bfloat16(v.y);
    c.h[2] = __float2bfloat16(v.z);
    c.h[3] = __float2bfloat16(v.w);
    reinterpret_cast<ushort4*>(xb)[idx] = c.u;
    return;
  }
  __shared__ float tile[32][33];
  const float* W;
  __hip_bfloat16* Wt;
  int K, N, kblk, nblk;
  int b2 = b - 6144;
  if (b2 < 1536) {                  // W1: 3072x512 -> 512x3072
    W = W1; Wt = W1t; K = 3072; N = 512;
    kblk = b2 % 96; nblk = b2 / 96;
  } else if (b2 < 1664) {           // W2: 512x256 -> 256x512
    int b3 = b2 - 1536;
    W = W2; Wt = W2t; K = 512; N = 256;
    kblk = b3 % 16; nblk = b3 / 16;
  } else {                          // T: 256x100 -> 128x256 (zero-pad n>=100)
    int b4 = b2 - 1664;
    W = T; Wt = Tt; K = 256; N = 100;
    kblk = b4 % 8; nblk = b4 / 8;
  }
  int k0 = kblk * 32, n0 = nblk * 32;
  int tx = t & 31, ty = t >> 5;  // 32 x 8
#pragma unroll
  for (int r = 0; r < 4; ++r) {
    int n = n0 + tx;
    tile[ty + r * 8][tx] = (n < N) ? W[(long)(k0 + ty + r * 8) * N + n] : 0.f;
  }
  __syncthreads();
#pragma unroll
  for (int r = 0; r < 4; ++r)
    Wt[(long)(n0 + ty + r * 8) * K + k0 + tx] = __float2bfloat16(tile[tx][ty + r * 8]);
}

// ---------- G1: P1[z] = xb @ W1t^T, split-K=3, BK=64 (r5-proven) ----------
__global__ __launch_bounds__(256) void k_gemm1(const __hip_bfloat16* __restrict__ A,
                                               const __hip_bfloat16* __restrict__ Bt,
                                               float* __restrict__ Cp) {
  const int K = 3072, N = 512, KSPL = 1024;
  __shared__ __align__(16) __hip_bfloat16 As[64][72];
  __shared__ __align__(16) __hip_bfloat16 Bs[64][72];
  int tid = threadIdx.x, lane = tid & 63, wv = tid >> 6;
  int wm = wv & 1, wn = wv >> 1, quad = lane >> 4, l16 = lane & 15;
  long m0 = (long)blockIdx.x * 64, n0 = (long)blockIdx.y * 64;
  int kStart = blockIdx.z * KSPL;
  int srow = tid >> 2, scol = (tid & 3) * 16;
  const __hip_bfloat16* Ag = A + (m0 + srow) * K + kStart + scol;
  const __hip_bfloat16* Bg = Bt + (n0 + srow) * K + kStart + scol;

  int4 ra0 = *reinterpret_cast<const int4*>(Ag);
  int4 ra1 = *reinterpret_cast<const int4*>(Ag + 8);
  int4 rb0 = *reinterpret_cast<const int4*>(Bg);
  int4 rb1 = *reinterpret_cast<const int4*>(Bg + 8);

  f32x4 acc[2][2] = {};
  for (int kb = 0; kb < KSPL; kb += 64) {
    *reinterpret_cast<int4*>(&As[srow][scol]) = ra0;
    *reinterpret_cast<int4*>(&As[srow][scol + 8]) = ra1;
    *reinterpret_cast<int4*>(&Bs[srow][scol]) = rb0;
    *reinterpret_cast<int4*>(&Bs[srow][scol + 8]) = rb1;
    __syncthreads();
    if (kb + 64 < KSPL) {
      ra0 = *reinterpret_cast<const int4*>(Ag + kb + 64);
      ra1 = *reinterpret_cast<const int4*>(Ag + kb + 72);
      rb0 = *reinterpret_cast<const int4*>(Bg + kb + 64);
      rb1 = *reinterpret_cast<const int4*>(Bg + kb + 72);
    }
#pragma unroll
    for (int half = 0; half < 2; ++half) {
      short8 af[2], bfr[2];
#pragma unroll
      for (int u = 0; u < 2; ++u) {
        af[u]  = *reinterpret_cast<const short8*>(&As[wm * 32 + u * 16 + l16][half * 32 + quad * 8]);
        bfr[u] = *reinterpret_cast<const short8*>(&Bs[wn * 32 + u * 16 + l16][half * 32 + quad * 8]);
      }
#pragma unroll
      for (int tm = 0; tm < 2; ++tm)
#pragma unroll
        for (int tn = 0; tn < 2; ++tn)
          acc[tm][tn] =
              __builtin_amdgcn_mfma_f32_16x16x32_bf16(af[tm], bfr[tn], acc[tm][tn], 0, 0, 0);
    }
    __syncthreads();
  }

  float* Cz = Cp + (long)blockIdx.z * 2048 * 512;
#pragma unroll
  for (int tm = 0; tm < 2; ++tm)
#pragma unroll
    for (int tn = 0; tn < 2; ++tn)
#pragma unroll
      for (int r = 0; r < 4; ++r) {
        long gm = m0 + wm * 32 + tm * 16 + quad * 4 + r;
        long gn = n0 + wn * 32 + tn * 16 + l16;
        Cz[gm * N + gn] = acc[tm][tn][r];
      }
}

// ---------- G2: h2b = leaky(h1 @ W2t^T + b2); h1 built on-stage from 3 P1 partials ----------
__global__ __launch_bounds__(256) void k_gemm2(const float* __restrict__ P1,
                                               const float* __restrict__ b1,
                                               const __hip_bfloat16* __restrict__ Bt,
                                               const float* __restrict__ b2,
                                               __hip_bfloat16* __restrict__ h2b) {
  const int K = 512, N = 256;
  const long FS = 2048L * 512;
  __shared__ __align__(16) __hip_bfloat16 As[64][72];
  __shared__ __align__(16) __hip_bfloat16 Bs[64][72];
  int tid = threadIdx.x, lane = tid & 63, wv = tid >> 6;
  int wm = wv & 1, wn = wv >> 1, quad = lane >> 4, l16 = lane & 15;
  long m0 = (long)blockIdx.x * 64, n0 = (long)blockIdx.y * 64;
  int srow = tid >> 2, scol = (tid & 3) * 16;
  const float* Ag = P1 + (m0 + srow) * K + scol;
  const __hip_bfloat16* Bg = Bt + (n0 + srow) * K + scol;

  auto loadA = [&](int kb, int4& o0, int4& o1) {
    float4 v[4];
#pragma unroll
    for (int j = 0; j < 4; ++j) v[j] = *reinterpret_cast<const float4*>(Ag + kb + j * 4);
#pragma unroll
    for (int z = 1; z < 3; ++z)
#pragma unroll
      for (int j = 0; j < 4; ++j) {
        float4 a = *reinterpret_cast<const float4*>(Ag + z * FS + kb + j * 4);
        v[j].x += a.x; v[j].y += a.y; v[j].z += a.z; v[j].w += a.w;
      }
#pragma unroll
    for (int j = 0; j < 4; ++j) {
      float4 bs = *reinterpret_cast<const float4*>(b1 + kb + scol + j * 4);
      v[j].x += bs.x; v[j].y += bs.y; v[j].z += bs.z; v[j].w += bs.w;
      v[j].x = v[j].x > 0.f ? v[j].x : LEAK * v[j].x;
      v[j].y = v[j].y > 0.f ? v[j].y : LEAK * v[j].y;
      v[j].z = v[j].z > 0.f ? v[j].z : LEAK * v[j].z;
      v[j].w = v[j].w > 0.f ? v[j].w : LEAK * v[j].w;
    }
    bfpack u0, u1;
    u0.h[0] = __float2bfloat16(v[0].x); u0.h[1] = __float2bfloat16(v[0].y);
    u0.h[2] = __float2bfloat16(v[0].z); u0.h[3] = __float2bfloat16(v[0].w);
    u0.h[4] = __float2bfloat16(v[1].x); u0.h[5] = __float2bfloat16(v[1].y);
    u0.h[6] = __float2bfloat16(v[1].z); u0.h[7] = __float2bfloat16(v[1].w);
    u1.h[0] = __float2bfloat16(v[2].x); u1.h[1] = __float2bfloat16(v[2].y);
    u1.h[2] = __float2bfloat16(v[2].z); u1.h[3] = __float2bfloat16(v[2].w);
    u1.h[4] = __float2bfloat16(v[3].x); u1.h[5] = __float2bfloat16(v[3].y);
    u1.h[6] = __float2bfloat16(v[3].z); u1.h[7] = __float2bfloat16(v[3].w);
    o0 = u0.i; o1 = u1.i;
  };

  int4 ra0, ra1, rb0, rb1;
  loadA(0, ra0, ra1);
  rb0 = *reinterpret_cast<const int4*>(Bg);
  rb1 = *reinterpret_cast<const int4*>(Bg + 8);

  f32x4 acc[2][2] = {};
  for (int kb = 0; kb < K; kb += 64) {
    *reinterpret_cast<int4*>(&As[srow][scol]) = ra0;
    *reinterpret_cast<int4*>(&As[srow][scol + 8]) = ra1;
    *reinterpret_cast<int4*>(&Bs[srow][scol]) = rb0;
    *reinterpret_cast<int4*>(&Bs[srow][scol + 8]) = rb1;
    __syncthreads();
    if (kb + 64 < K) {
      loadA(kb + 64, ra0, ra1);
      rb0 = *reinterpret_cast<const int4*>(Bg + kb + 64);
      rb1 = *reinterpret_cast<const int4*>(Bg + kb + 72);
    }
#pragma unroll
    for (int half = 0; half < 2; ++half) {
      short8 af[2], bfr[2];
#pragma unroll
      for (int u = 0; u < 2; ++u) {
        af[u]  = *reinterpret_cast<const short8*>(&As[wm * 32 + u * 16 + l16][half * 32 + quad * 8]);
        bfr[u] = *reinterpret_cast<const short8*>(&Bs[wn * 32 + u * 16 + l16][half * 32 + quad * 8]);
      }
#pragma unroll
      for (int tm = 0; tm < 2; ++tm)
#pragma unroll
        for (int tn = 0; tn < 2; ++tn)
          acc[tm][tn] =
              __builtin_amdgcn_mfma_f32_16x16x32_bf16(af[tm], bfr[tn], acc[tm][tn], 0, 0, 0);
    }
    __syncthreads();
  }

#pragma unroll
  for (int tm = 0; tm < 2; ++tm)
#pragma unroll
    for (int tn = 0; tn < 2; ++tn)
#pragma unroll
      for (int r = 0; r < 4; ++r) {
        long gm = m0 + wm * 32 + tm * 16 + quad * 4 + r;
        long gn = n0 + wn * 32 + tn * 16 + l16;
        float v = acc[tm][tn][r] + b2[gn];
        v = v > 0.f ? v : LEAK * v;
        h2b[gm * N + gn] = __float2bfloat16(v);
      }
}

// ---------- G3: P3[z] = (h2b @ Tt^T)^T, split-K=4, transposed partials ----------
__global__ __launch_bounds__(256) void k_gemm3(const __hip_bfloat16* __restrict__ A,
                                               const __hip_bfloat16* __restrict__ Bt,
                                               float* __restrict__ Cp) {
  const int K = 256;
  __shared__ __align__(16) __hip_bfloat16 As[64][72];
  __shared__ __align__(16) __hip_bfloat16 Bs[64][72];
  int tid = threadIdx.x;
  int lane = tid & 63, wv = tid >> 6;
  int wm = wv & 1, wn = wv >> 1, quad = lane >> 4, l16 = lane & 15;
  long m0 = (long)blockIdx.x * 64, n0 = (long)blockIdx.y * 64;
  int kStart = blockIdx.z * 64;
  int srow = tid >> 2, scol = (tid & 3) * 16;
  const __hip_bfloat16* Ag = A + (m0 + srow) * K + kStart + scol;
  const __hip_bfloat16* Bg = Bt + (n0 + srow) * K + kStart + scol;

  *reinterpret_cast<int4*>(&As[srow][scol]) = *reinterpret_cast<const int4*>(Ag);
  *reinterpret_cast<int4*>(&As[srow][scol + 8]) = *reinterpret_cast<const int4*>(Ag + 8);
  *reinterpret_cast<int4*>(&Bs[srow][scol]) = *reinterpret_cast<const int4*>(Bg);
  *reinterpret_cast<int4*>(&Bs[srow][scol + 8]) = *reinterpret_cast<const int4*>(Bg + 8);
  __syncthreads();
  f32x4 acc[2][2] = {};
#pragma unroll
  for (int half = 0; half < 2; ++half) {
    short8 af[2], bfr[2];
#pragma unroll
    for (int u = 0; u < 2; ++u) {
      af[u]  = *reinterpret_cast<const short8*>(&As[wm * 32 + u * 16 + l16][half * 32 + quad * 8]);
      bfr[u] = *reinterpret_cast<const short8*>(&Bs[wn * 32 + u * 16 + l16][half * 32 + quad * 8]);
    }
#pragma unroll
    for (int tm = 0; tm < 2; ++tm)
#pragma unroll
      for (int tn = 0; tn < 2; ++tn)
        acc[tm][tn] =
            __builtin_amdgcn_mfma_f32_16x16x32_bf16(af[tm], bfr[tn], acc[tm][tn], 0, 0, 0);
  }
  float* Cz = Cp + (long)blockIdx.z * 2048 * 128;
#pragma unroll
  for (int tm = 0; tm < 2; ++tm)
#pragma unroll
    for (int tn = 0; tn < 2; ++tn)
#pragma unroll
      for (int r = 0; r < 4; ++r) {
        long gm = m0 + wm * 32 + tm * 16 + quad * 4 + r;
        long gn = n0 + wn * 32 + tn * 16 + l16;
        Cz[gn * 2048 + gm] = acc[tm][tn][r];  // transposed partial: mTz[n][m]
      }
}

// ---------- bucketed minibatch-discrimination features, O(B) ----------
__global__ __launch_bounds__(1024) void k_bucketfeats(const float* __restrict__ mTz,
                                                      float* __restrict__ featsT) {
  __shared__ float sP[2048], sN[2048];
  __shared__ float Sp[2048], Sn[2048];
  __shared__ int Smeta[2048];
  __shared__ short sB[2048];
  __shared__ int cnt[256], bstart[256], bcur[256];
  __shared__ float bsP[256], bsN[256], Pbel[256], Nab[256];
  __shared__ float wred[32];
  __shared__ float sMin, sMax;
  int f = blockIdx.x;
  int t = threadIdx.x;
  int lane = t & 63, wv = t >> 6;
  const long FS = 2048L * 128;
  const float* row = mTz + (long)f * 2048;

  float m[2];
  float lmin = 3.4e38f, lmax = -3.4e38f;
#pragma unroll
  for (int r = 0; r < 2; ++r) {
    int e = t + r * 1024;
    float v = row[e] + row[FS + e] + row[2 * FS + e] + row[3 * FS + e];
    m[r] = v;
    lmin = fminf(lmin, v);
    lmax = fmaxf(lmax, v);
  }
#pragma unroll
  for (int d = 32; d; d >>= 1) {
    lmin = fminf(lmin, __shfl_down(lmin, d));
    lmax = fmaxf(lmax, __shfl_down(lmax, d));
  }
  if (lane == 0) { wred[wv] = lmin; wred[16 + wv] = lmax; }
  if (t < 256) cnt[t] = 0;
  __syncthreads();
  if (t == 0) {
    float a = wred[0], b = wred[16];
    for (int i = 1; i < 16; ++i) { a = fminf(a, wred[i]); b = fmaxf(b, wred[16 + i]); }
    sMin = a; sMax = b;
  }
  __syncthreads();
  float mn = sMin, mx = sMax;
  float rge = mx - mn;
  float scale = (rge > 1e-20f) ? 255.0f / rge : 0.f;
  float mid = 0.5f * (mn + mx);
#pragma unroll
  for (int r = 0; r < 2; ++r) {
    int e = t + r * 1024;
    float v = m[r];
    int b = (int)((v - mn) * scale);
    b = b < 255 ? b : 255;
    float arg = fminf(fmaxf(v - mid, -60.f), 60.f);
    sP[e] = __expf(arg);
    sN[e] = __expf(-arg);
    sB[e] = (short)b;
    atomicAdd(&cnt[b], 1);
  }
  __syncthreads();
  if (wv == 0) {
    int b4 = lane * 4;
    int c0 = cnt[b4], c1 = cnt[b4 + 1], c2 = cnt[b4 + 2], c3 = cnt[b4 + 3];
    int tot = c0 + c1 + c2 + c3;
    int inc = tot;
#pragma unroll
    for (int d = 1; d < 64; d <<= 1) {
      int y = __shfl_up(inc, d);
      if (lane >= d) inc += y;
    }
    int run = inc - tot;
    bstart[b4] = run; bcur[b4] = run; run += c0;
    bstart[b4 + 1] = run; bcur[b4 + 1] = run; run += c1;
    bstart[b4 + 2] = run; bcur[b4 + 2] = run; run += c2;
    bstart[b4 + 3] = run; bcur[b4 + 3] = run;
  }
  __syncthreads();
#pragma unroll
  for (int r = 0; r < 2; ++r) {
    int e = t + r * 1024;
    int b = sB[e];
    int slot = atomicAdd(&bcur[b], 1);
    Sp[slot] = sP[e];
    Sn[slot] = sN[e];
    Smeta[slot] = (b << 16) | e;
  }
  __syncthreads();
  if (t < 256) {
    int s0 = bstart[t], s1 = s0 + cnt[t];
    float ap = 0.f, an = 0.f;
    for (int q = s0; q < s1; ++q) { ap += Sp[q]; an += Sn[q]; }
    bsP[t] = ap; bsN[t] = an;
  }
  __syncthreads();
  if (wv == 0) {
    int b4 = lane * 4;
    float p0 = bsP[b4], p1 = bsP[b4 + 1], p2 = bsP[b4 + 2], p3 = bsP[b4 + 3];
    float n0 = bsN[b4], n1 = bsN[b4 + 1], n2 = bsN[b4 + 2], n3 = bsN[b4 + 3];
    float tp = p0 + p1 + p2 + p3, tn = n0 + n1 + n2 + n3;
    float ip = tp, in_ = tn;
#pragma unroll
    for (int d = 1; d < 64; d <<= 1) {
      float yp = __shfl_up(ip, d);
      float yn = __shfl_up(in_, d);
      if (lane >= d) { ip += yp; in_ += yn; }
    }
    float totn = __shfl(in_, 63);
    float runp = ip - tp;
    float runn = in_ - tn;
    Pbel[b4] = runp; Nab[b4] = totn - runn - n0; runp += p0; runn += n0;
    Pbel[b4 + 1] = runp; Nab[b4 + 1] = totn - runn - n1; runp += p1; runn += n1;
    Pbel[b4 + 2] = runp; Nab[b4 + 2] = totn - runn - n2; runp += p2; runn += n2;
    Pbel[b4 + 3] = runp; Nab[b4 + 3] = totn - runn - n3;
  }
  __syncthreads();
#pragma unroll
  for (int r = 0; r < 2; ++r) {
    int s = t + r * 1024;
    int meta = Smeta[s];
    int b = meta >> 16;
    int idx = meta & 0xFFFF;
    float p = Sp[s], n = Sn[s];
    float acc = n * Pbel[b] + p * Nab[b];
    int q0 = bstart[b], q1 = q0 + cnt[b];
    for (int q = q0; q < q1; ++q) acc += fminf(p * Sn[q], n * Sp[q]);
    featsT[(long)f * 2048 + idx] = acc;
  }
}

// ---------- final: out[i] = h2b[i,:].Wf[0:256] + featsT[:,i].Wf[256:356] + bf ----------
__global__ __launch_bounds__(256) void k_final(const __hip_bfloat16* __restrict__ h2b,
                                               const float* __restrict__ featsT,
                                               const float* __restrict__ Wf,
                                               const float* __restrict__ bfp,
                                               float* __restrict__ out) {
  int wv = threadIdx.x >> 6, lane = threadIdx.x & 63;
  long i = (long)blockIdx.x * 4 + wv;
  const unsigned short* hrow = reinterpret_cast<const unsigned short*>(h2b) + i * 256;
  float s = 0.f;
#pragma unroll
  for (int c = lane; c < 256; c += 64) s += bf2f(hrow[c]) * Wf[c];
  for (int f = lane; f < 100; f += 64) s += featsT[(long)f * 2048 + i] * Wf[256 + f];
#pragma unroll
  for (int off = 32; off; off >>= 1) s += __shfl_down(s, off);
  if (lane == 0) out[i] = s + bfp[0];
}

extern "C" void kernel_launch(void* const* d_in, const int* in_sizes, int n_in,
                              void* d_out, int out_size, void* d_ws, size_t ws_size,
                              hipStream_t stream) {
  const float* x  = (const float*)d_in[0];
  const float* W1 = (const float*)d_in[1];
  const float* b1 = (const float*)d_in[2];
  const float* W2 = (const float*)d_in[3];
  const float* b2 = (const float*)d_in[4];
  const float* T  = (const float*)d_in[5];
  const float* Wf = (const float*)d_in[6];
  const float* bf = (const float*)d_in[7];
  float* out = (float*)d_out;

  char* w = (char*)d_ws;
  auto alloc = [&](size_t b) { char* p = w; w += (b + 255) & ~(size_t)255; return p; };
  __hip_bfloat16* xb  = (__hip_bfloat16*)alloc(2048L * 3072 * 2);  // 12 MB
  __hip_bfloat16* W1t = (__hip_bfloat16*)alloc(512L * 3072 * 2);   // 3 MB
  __hip_bfloat16* W2t = (__hip_bfloat16*)alloc(256L * 512 * 2);
  __hip_bfloat16* Tt  = (__hip_bfloat16*)alloc(128L * 256 * 2);
  __hip_bfloat16* h2b = (__hip_bfloat16*)alloc(2048L * 256 * 2);   // 1 MB
  float*          feT = (float*)alloc(100L * 2048 * 4);            // 0.8 MB
  float*          P1  = (float*)alloc(3L * 2048 * 512 * 4);        // 12 MB
  float*          P3  = (float*)alloc(4L * 2048 * 128 * 4);        // 4 MB

  // 1) prep: x->bf16 + W1t + W2t + Tt
  k_prep<<<7840, 256, 0, stream>>>(x, xb, W1, W1t, W2, W2t, T, Tt);
  // 2) G1: xb @ W1t, split-K=3 (768 blocks, 3/CU)
  k_gemm1<<<dim3(32, 8, 3), 256, 0, stream>>>(xb, W1t, P1);
  // 3) G2: (comb1 fused on stage) @ W2t, full-K, fused b2+leaky -> h2b
  k_gemm2<<<dim3(32, 4), 256, 0, stream>>>(P1, b1, W2t, b2, h2b);
  // 4) G3: h2b @ Tt, split-K=4, transposed partials
  k_gemm3<<<dim3(32, 2, 4), 256, 0, stream>>>(h2b, Tt, P3);
  // 5) bucketed features
  k_bucketfeats<<<100, 1024, 0, stream>>>(P3, feT);
  // 6) final dot
  k_final<<<512, 256, 0, stream>>>(h2b, feT, Wf, bf, out);
}